// Round 13
// baseline (1204.217 us; speedup 1.0000x reference)
//
#include <hip/hip_runtime.h>
#include <math.h>

// ---------------- problem constants ----------------
#define NN 50000      // nodes
#define NE 150000     // edges
#define NG 2000       // graphs
#define NL 4          // layers
#define AVG_DEG_LOG 1.1308269950720915f
// Hsrc/etab channel axis padded per tower: 5 towers x 80 = 400 (pad channels are exact zeros)

typedef __attribute__((ext_vector_type(8))) short bf8_t;
typedef __attribute__((ext_vector_type(4))) float f4_t;

__device__ inline unsigned short f2bf(float x) {
  union { float f; unsigned int u; } v; v.f = x;
  unsigned int r = (v.u + 0x7FFFu + ((v.u >> 16) & 1u)) >> 16;
  return (unsigned short)r;
}
__device__ inline float bflo(unsigned int u) { union { unsigned int u; float f; } v; v.u = u << 16; return v.f; }
__device__ inline float bfhi(unsigned int u) { union { unsigned int u; float f; } v; v.u = u & 0xFFFF0000u; return v.f; }

// BN(+relu)-applied bf16 fragment load from Zf row (stride 76 f32). k0 in {0,8,...,88}.
__device__ inline bf8_t ldfrag(const float* __restrict__ zrow, int k0, int bn,
                               const float* __restrict__ musig,
                               const float* __restrict__ gm, const float* __restrict__ bt) {
  bf8_t r;
  #pragma unroll
  for (int j = 0; j < 8; ++j) {
    int k = k0 + j;
    float x = 0.0f;
    if (k < 75) {
      x = zrow[k];
      if (bn) x = fmaxf(gm[k] * (x - musig[k]) * musig[75 + k] + bt[k], 0.0f);
    }
    r[j] = (short)f2bf(x);
  }
  return r;
}

// ---------------- preprocessing ----------------
__global__ void k_deg(const int* __restrict__ dst, int* __restrict__ deg) {
  int e = blockIdx.x * 256 + threadIdx.x;
  if (e < NE) atomicAdd(&deg[dst[e]], 1);
}

__global__ __launch_bounds__(1024) void k_scan(const int* __restrict__ deg, int* __restrict__ off) {
  __shared__ int wsum[16];
  __shared__ int wpre[16];
  __shared__ int carry_s;
  int tid = threadIdx.x, lane = tid & 63, wv = tid >> 6;
  if (tid == 0) carry_s = 0;
  __syncthreads();
  for (int base = 0; base < NN; base += 1024) {
    int i = base + tid;
    int v = (i < NN) ? deg[i] : 0;
    int incl = v;
    #pragma unroll
    for (int d = 1; d < 64; d <<= 1) { int t = __shfl_up(incl, d); if (lane >= d) incl += t; }
    if (lane == 63) wsum[wv] = incl;
    __syncthreads();
    if (wv == 0) {
      int s = (lane < 16) ? wsum[lane] : 0;
      int sc = s;
      #pragma unroll
      for (int d = 1; d < 16; d <<= 1) { int t = __shfl_up(sc, d); if (lane >= d) sc += t; }
      if (lane < 16) wpre[lane] = sc - s;
    }
    __syncthreads();
    int carry = carry_s;
    int excl = carry + wpre[wv] + incl - v;
    if (i < NN) off[i] = excl;
    __syncthreads();
    if (tid == 1023) carry_s = excl + v;
    __syncthreads();
  }
  if (tid == 0) off[NN] = carry_s;
}

__global__ void k_amp(const int* __restrict__ deg, const int* __restrict__ off,
                      float* __restrict__ amp, float* __restrict__ invamp,
                      float* __restrict__ gate, int* __restrict__ cursor) {
  int n = blockIdx.x * 256 + threadIdx.x;
  if (n < NN) {
    int d0 = deg[n];
    int d = d0 < 1 ? 1 : d0;
    float a = logf((float)d + 1.0f) / AVG_DEG_LOG;
    amp[n] = a; invamp[n] = 1.0f / a;
    gate[n] = (d0 > 0) ? 1.0f : 0.0f;
    cursor[n] = off[n];
  }
}

__global__ void k_fill(const int* __restrict__ src, const int* __restrict__ dst,
                       const int* __restrict__ attr, int* __restrict__ cursor,
                       unsigned int* __restrict__ cpack) {
  int e = blockIdx.x * 256 + threadIdx.x;
  if (e < NE) {
    int d = dst[e];
    int p = atomicAdd(&cursor[d], 1);
    cpack[p] = (unsigned int)src[e] | ((unsigned int)attr[e] << 16);
  }
}

// node embedding -> Zf f32 [NN][76] (col 75 zero). Layer 0 reads Zf raw (bn=0).
__global__ void k_embed(const int* __restrict__ x, const float* __restrict__ emb, float* __restrict__ Zf) {
  int i = blockIdx.x * 256 + threadIdx.x;
  if (i < NN * 76) {
    int n = i / 76, c = i - (i / 76) * 76;
    Zf[i] = (c < 75) ? emb[x[n] * 75 + c] : 0.0f;
  }
}

// ---------------- weight prep ----------------
__global__ void k_wxlin(const float* __restrict__ Wpost, const float* __restrict__ Wlin, float* __restrict__ WXlin) {
  int l = blockIdx.x;
  for (int idx = threadIdx.x; idx < 5625; idx += 256) {
    int k = idx / 75, j = idx - (idx / 75) * 75;
    float s = 0.0f;
    for (int o = 0; o < 75; ++o) {
      int t = o / 15, jj = o - t * 15;
      s += Wpost[((l * 5 + t) * 975 + k) * 15 + jj] * Wlin[l * 5625 + o * 75 + j];
    }
    WXlin[l * 5625 + idx] = s;
  }
}

__global__ void k_zb(const float* __restrict__ bpost, const float* __restrict__ blin,
                     const float* __restrict__ Wlin, float* __restrict__ zb) {
  int l = blockIdx.x, j = threadIdx.x;
  if (j < 75) {
    float s = blin[l * 75 + j];
    for (int o = 0; o < 75; ++o) s += bpost[l * 75 + o] * Wlin[l * 5625 + o * 75 + j];
    zb[l * 75 + j] = s;
  }
}

// WY[l][s][k][o], bY[l][s][o]: cd-path composed weights
__global__ void k_wy(const float* __restrict__ Wpre, const float* __restrict__ bpre,
                     const float* __restrict__ Wpost, float* __restrict__ WY, float* __restrict__ bY) {
  __shared__ float wsum[1125];
  int b = blockIdx.x;                 // l*15 + t*3 + s
  int l = b / 15, rr = b - l * 15, t = rr / 3, s = rr - (rr / 3) * 3;
  int tid = threadIdx.x;
  for (int it = tid; it < 1125; it += 256) {
    int f = it / 15, jj = it - (it / 15) * 15;
    float acc = 0.0f;
    #pragma unroll
    for (int agg = 0; agg < 3; ++agg)
      acc += Wpost[((l * 5 + t) * 975 + 75 + s * 300 + agg * 75 + f) * 15 + jj];
    wsum[f * 15 + jj] = acc;
  }
  __syncthreads();
  for (int it = tid; it < 1140; it += 256) {
    int k = it / 15, jj = it - (it / 15) * 15;
    float acc = 0.0f;
    if (k < 75) {
      for (int f = 0; f < 75; ++f)
        acc += Wpre[((l * 5 + t) * 225 + k) * 75 + f] * wsum[f * 15 + jj];
      WY[((l * 3 + s) * 75 + k) * 75 + t * 15 + jj] = acc;
    } else {
      for (int f = 0; f < 75; ++f)
        acc += bpre[l * 375 + t * 75 + f] * wsum[f * 15 + jj];
      bY[(l * 3 + s) * 75 + t * 15 + jj] = acc;
    }
  }
}

// packs: B1Ts [4][400][96] (c = t*80+f, f<75 real); WXYT [4][320][96]; WlinT [4][80][96]
__global__ void k_packAll(const float* __restrict__ Wpre, const float* __restrict__ WXlin,
                          const float* __restrict__ WY, const float* __restrict__ Wlin,
                          unsigned short* __restrict__ B1Ts, unsigned short* __restrict__ WXYT,
                          unsigned short* __restrict__ WlinT) {
  const int S1 = 4 * 400 * 96;
  const int S2 = S1 + 4 * 320 * 96;
  const int S3 = S2 + 4 * 80 * 96;
  int idx = blockIdx.x * 256 + threadIdx.x;
  if (idx < S1) {
    int l = idx / (400 * 96); int rem = idx - l * (400 * 96);
    int c = rem / 96, k = rem - (rem / 96) * 96;
    int t = c / 80, f = c - t * 80;
    float v = 0.0f;
    if (f < 75 && k < 75)
      v = Wpre[((l * 5 + t) * 225 + 75 + k) * 75 + f];
    B1Ts[idx] = f2bf(v);
  } else if (idx < S2) {
    int m = idx - S1;
    int l = m / (320 * 96); int rem = m - l * (320 * 96);
    int c = rem / 96, k = rem - (rem / 96) * 96;
    float v = 0.0f;
    if (k < 75) {
      if (c < 80) {
        if (c < 75) v = WXlin[l * 5625 + k * 75 + c];
      } else {
        int g = c - 80; int t = g / 48; int r = g - t * 48; int s = r / 16; int jj = r - s * 16;
        if (jj < 15) v = WY[((l * 3 + s) * 75 + k) * 75 + t * 15 + jj];
      }
    }
    WXYT[m] = f2bf(v);
  } else if (idx < S3) {
    int m = idx - S2;
    int l = m / (80 * 96); int rem = m - l * (80 * 96);
    int j = rem / 96, k = rem - (rem / 96) * 96;
    float v = (j < 75 && k < 75) ? Wlin[l * 5625 + k * 75 + j] : 0.0f;
    WlinT[m] = f2bf(v);
  }
}

// WcombT bf16 [4][5][48][320]: row j=s*15+jj (45 real), col k = f*4+agg, f in [0,80) (f<75 real)
__global__ void k_packWcomb(const float* __restrict__ Wpost, unsigned short* __restrict__ WcombT) {
  int idx = blockIdx.x * 256 + threadIdx.x;
  if (idx >= 4 * 5 * 48 * 320) return;
  int l = idx / (5 * 48 * 320); int rem = idx - l * (5 * 48 * 320);
  int t = rem / (48 * 320); rem -= t * (48 * 320);
  int j = rem / 320, k = rem - (rem / 320) * 320;
  int f = k >> 2, agg = k & 3;
  float v = 0.0f;
  if (j < 45 && f < 75) {
    int s = j / 15, jj = j - s * 15;
    v = Wpost[((l * 5 + t) * 975 + 75 + s * 300 + agg * 75 + f) * 15 + jj];
  }
  WcombT[idx] = f2bf(v);
}

// etab f32 [4][4][400] (c = t*80+f; f>=75 pads zero)
__global__ void k_etab(const float* __restrict__ edge_emb, const float* __restrict__ We,
                       const float* __restrict__ be, const float* __restrict__ Wpre,
                       float* __restrict__ etab) {
  __shared__ float ev[75];
  int l = blockIdx.x >> 2, a = blockIdx.x & 3;
  int tid = threadIdx.x;
  if (tid < 75) {
    float acc = be[l * 75 + tid];
    for (int k = 0; k < 50; ++k) acc += edge_emb[a * 50 + k] * We[(l * 50 + k) * 75 + tid];
    ev[tid] = acc;
  }
  __syncthreads();
  for (int c = tid; c < 400; c += 256) {
    int t = c / 80, f = c - t * 80;
    float acc = 0.0f;
    if (f < 75) {
      for (int d = 0; d < 75; ++d) acc += ev[d] * Wpre[((l * 5 + t) * 225 + 150 + d) * 75 + f];
    }
    etab[(l * 4 + a) * 400 + c] = acc;
  }
}

// ---------------- GEMM1 (MFMA): Hsrc = BN(Zf) @ B1Ts -> bf16 [NN][400]; hb bf16 [NN][96]. LDS-transpose epilogue.
__global__ __launch_bounds__(256) void k_gemm1(const float* __restrict__ Zf,
                                               const float* __restrict__ bnsum,
                                               const float* __restrict__ gm, const float* __restrict__ bt,
                                               int bn,
                                               const unsigned short* __restrict__ B1Ts_l,
                                               unsigned short* __restrict__ Hsrc,
                                               unsigned short* __restrict__ hb) {
  __shared__ float ms_s[150];
  __shared__ __align__(16) unsigned short H_s[64 * 408];
  int tid = threadIdx.x;
  if (tid < 75) {
    float mu = bnsum[tid] * (1.0f / NN);
    float var = fmaxf(bnsum[75 + tid] * (1.0f / NN) - mu * mu, 0.0f);
    ms_s[tid] = mu;
    ms_s[75 + tid] = 1.0f / sqrtf(var + 1e-5f);
  }
  __syncthreads();
  int w = tid >> 6, lane = tid & 63;
  int l15 = lane & 15, l4 = lane >> 4;
  int m0 = blockIdx.x * 64;
  int mA = m0 + w * 16 + l15; if (mA >= NN) mA = NN - 1;
  const float* zrow = Zf + (size_t)mA * 76;
  bf8_t a0 = ldfrag(zrow, l4 * 8, bn, ms_s, gm, bt);
  bf8_t a1 = ldfrag(zrow, 32 + l4 * 8, bn, ms_s, gm, bt);
  bf8_t a2 = ldfrag(zrow, 64 + l4 * 8, bn, ms_s, gm, bt);
  {
    unsigned short* hrow = hb + (size_t)mA * 96 + l4 * 8;
    *(bf8_t*)(hrow) = a0;
    *(bf8_t*)(hrow + 32) = a1;
    *(bf8_t*)(hrow + 64) = a2;
  }
  for (int nf = 0; nf < 25; ++nf) {
    int c = nf * 16 + l15;
    const unsigned short* bp = B1Ts_l + (size_t)c * 96 + l4 * 8;
    f4_t acc = {0.f, 0.f, 0.f, 0.f};
    acc = __builtin_amdgcn_mfma_f32_16x16x32_bf16(a0, *(const bf8_t*)(bp), acc, 0, 0, 0);
    acc = __builtin_amdgcn_mfma_f32_16x16x32_bf16(a1, *(const bf8_t*)(bp + 32), acc, 0, 0, 0);
    acc = __builtin_amdgcn_mfma_f32_16x16x32_bf16(a2, *(const bf8_t*)(bp + 64), acc, 0, 0, 0);
    #pragma unroll
    for (int i = 0; i < 4; ++i)
      H_s[(w * 16 + l4 * 4 + i) * 408 + c] = f2bf(acc[i]);
  }
  __syncthreads();
  // flush 64 x 400 shorts via 16B stores
  for (int idx = tid; idx < 3200; idx += 256) {
    int row = idx / 50, q = idx - row * 50;
    int m = m0 + row;
    if (m < NN)
      *(uint4*)&Hsrc[(size_t)m * 400 + q * 8] = *(const uint4*)&H_s[row * 408 + q * 8];
  }
}

// ---------------- gather: 1 node/wave, 50 lanes x 8 channels (one tower each), A [5][NN][320] bf16 ----
__global__ __launch_bounds__(256) void k_gather(const unsigned short* __restrict__ Hsrc,
                                                const int* __restrict__ off,
                                                const unsigned int* __restrict__ cpack,
                                                const float* __restrict__ etab_l,
                                                unsigned short* __restrict__ A) {
  __shared__ float et_s[1600];
  int tid = threadIdx.x, w = tid >> 6, lane = tid & 63;
  for (int it = tid; it < 1600; it += 256) {
    int aa = it / 400, c = it - aa * 400;
    et_s[aa * 400 + (c ^ (((c >> 3) & 7) << 2))] = etab_l[it];
  }
  __syncthreads();
  if (lane >= 50) return;
  int g = blockIdx.x * 4 + w;
  int e0 = off[g], e1 = off[g + 1];
  int c0 = lane * 8;
  int cs = c0 ^ (((c0 >> 3) & 7) << 2);
  int t = lane / 10;
  int f0 = c0 - t * 80;
  const bf8_t* hbase = (const bf8_t*)Hsrc + lane;   // row stride 50 bf8 units
  float s8[8], q8[8], mn8[8], mx8[8];
  #pragma unroll
  for (int j = 0; j < 8; ++j) {
    s8[j] = 0.0f; q8[j] = 0.0f;
    mn8[j] = 3.402823466e+38f; mx8[j] = -3.402823466e+38f;
  }
  auto acc8 = [&](bf8_t hv, unsigned int aa) {
    union { bf8_t v; unsigned int u[4]; } cv; cv.v = hv;
    f4_t ea = *(const f4_t*)&et_s[aa * 400 + cs];
    f4_t eb = *(const f4_t*)&et_s[aa * 400 + (cs ^ 4)];
    #pragma unroll
    for (int j = 0; j < 8; ++j) {
      float h = (j & 1) ? bfhi(cv.u[j >> 1]) : bflo(cv.u[j >> 1]);
      float e = (j < 4) ? ea[j] : eb[j - 4];
      float q = h + e;
      s8[j] += q;
      q8[j] = fmaf(q, q, q8[j]);
      mn8[j] = fminf(mn8[j], q);
      mx8[j] = fmaxf(mx8[j], q);
    }
  };
  for (int e = e0; e < e1; ) {
    int m = e1 - e;
    unsigned int pk0 = cpack[e];
    unsigned int pk1 = cpack[m > 1 ? e + 1 : e];
    unsigned int pk2 = cpack[m > 2 ? e + 2 : e];
    unsigned int pk3 = cpack[m > 3 ? e + 3 : e];
    bf8_t h0 = hbase[(pk0 & 0xFFFFu) * 50];
    bf8_t h1 = hbase[(pk1 & 0xFFFFu) * 50];
    bf8_t h2 = hbase[(pk2 & 0xFFFFu) * 50];
    bf8_t h3 = hbase[(pk3 & 0xFFFFu) * 50];
    acc8(h0, pk0 >> 16);
    if (m > 1) acc8(h1, pk1 >> 16);
    if (m > 2) acc8(h2, pk2 >> 16);
    if (m > 3) acc8(h3, pk3 >> 16);
    e += (m < 4) ? m : 4;
  }
  int d = e1 - e0;
  unsigned short* abase = A + ((size_t)t * NN + g) * 320 + f0 * 4;
  uint4 pk[4];
  unsigned int* pw = (unsigned int*)pk;
  if (d > 0) {
    float inv = 1.0f / (float)d;
    #pragma unroll
    for (int j = 0; j < 8; ++j) {
      float mu = s8[j] * inv;
      float sd = sqrtf(fmaxf(q8[j] * inv - mu * mu, 0.0f) + 1e-5f);
      pw[j * 2]     = (unsigned int)f2bf(mu) | ((unsigned int)f2bf(mn8[j]) << 16);
      pw[j * 2 + 1] = (unsigned int)f2bf(mx8[j]) | ((unsigned int)f2bf(sd) << 16);
    }
  } else {
    unsigned int zsd = (unsigned int)f2bf(0.0031622776601683794f) << 16;
    #pragma unroll
    for (int j = 0; j < 8; ++j) { pw[j * 2] = 0u; pw[j * 2 + 1] = zsd; }
  }
  #pragma unroll
  for (int jj = 0; jj < 4; ++jj) *(uint4*)(abase + jj * 8) = pk[jj];
}

// ---------------- ptower: one (64-node, tower) tile per block; A@Wcomb + Y + combine -> Cbg ----------------
__global__ __launch_bounds__(256) void k_ptower(const unsigned short* __restrict__ A,
                                                const unsigned short* __restrict__ hb,
                                                const unsigned short* __restrict__ WcombT_l,
                                                const unsigned short* __restrict__ WXYT_l,
                                                const float* __restrict__ ampv,
                                                const float* __restrict__ invampv,
                                                const float* __restrict__ gatev,
                                                const float* __restrict__ bY_l,
                                                unsigned short* __restrict__ Cbg) {
  __shared__ __align__(16) float Out_s[64 * 99];   // cols 0-47 tower, 48-95 Y
  __shared__ float amp_s[64], inv_s[64], gate_s[64];
  __shared__ float bY_s[45];
  int tid = threadIdx.x;
  int w = tid >> 6, lane = tid & 63;
  int l15 = lane & 15, l4 = lane >> 4;
  int t = blockIdx.x;
  int m0 = blockIdx.y * 64;

  for (int r = tid; r < 64; r += 256) {
    int m = m0 + r; if (m >= NN) m = NN - 1;
    amp_s[r] = ampv[m]; inv_s[r] = invampv[m]; gate_s[r] = gatev[m];
  }
  if (tid < 45) {
    int s = tid / 15, jj = tid - s * 15;
    bY_s[tid] = bY_l[s * 75 + t * 15 + jj];
  }
  int mh = m0 + w * 16 + l15; if (mh >= NN) mh = NN - 1;
  const unsigned short* arow = A + ((size_t)t * NN + mh) * 320 + l4 * 8;
  bf8_t af[10];
  #pragma unroll
  for (int ks = 0; ks < 10; ++ks) af[ks] = *(const bf8_t*)(arow + ks * 32);
  const unsigned short* hrow = hb + (size_t)mh * 96 + l4 * 8;
  bf8_t hb0 = *(const bf8_t*)(hrow);
  bf8_t hb1 = *(const bf8_t*)(hrow + 32);
  bf8_t hb2 = *(const bf8_t*)(hrow + 64);

  f4_t tw0 = {0.f,0.f,0.f,0.f}, tw1 = {0.f,0.f,0.f,0.f}, tw2 = {0.f,0.f,0.f,0.f};
  const unsigned short* wp0 = WcombT_l + (size_t)(t * 48 + l15) * 320 + l4 * 8;
  const unsigned short* wp1 = WcombT_l + (size_t)(t * 48 + 16 + l15) * 320 + l4 * 8;
  const unsigned short* wp2 = WcombT_l + (size_t)(t * 48 + 32 + l15) * 320 + l4 * 8;
  #pragma unroll
  for (int ks = 0; ks < 10; ++ks) {
    tw0 = __builtin_amdgcn_mfma_f32_16x16x32_bf16(af[ks], *(const bf8_t*)(wp0 + ks * 32), tw0, 0, 0, 0);
    tw1 = __builtin_amdgcn_mfma_f32_16x16x32_bf16(af[ks], *(const bf8_t*)(wp1 + ks * 32), tw1, 0, 0, 0);
    tw2 = __builtin_amdgcn_mfma_f32_16x16x32_bf16(af[ks], *(const bf8_t*)(wp2 + ks * 32), tw2, 0, 0, 0);
  }
  f4_t yv[3];
  #pragma unroll
  for (int s = 0; s < 3; ++s) {
    const unsigned short* bp = WXYT_l + (size_t)(80 + t * 48 + s * 16 + l15) * 96 + l4 * 8;
    f4_t acc = {0.f, 0.f, 0.f, 0.f};
    acc = __builtin_amdgcn_mfma_f32_16x16x32_bf16(hb0, *(const bf8_t*)(bp), acc, 0, 0, 0);
    acc = __builtin_amdgcn_mfma_f32_16x16x32_bf16(hb1, *(const bf8_t*)(bp + 32), acc, 0, 0, 0);
    acc = __builtin_amdgcn_mfma_f32_16x16x32_bf16(hb2, *(const bf8_t*)(bp + 64), acc, 0, 0, 0);
    yv[s] = acc;
  }
  #pragma unroll
  for (int i = 0; i < 4; ++i) {
    int rb = w * 16 + l4 * 4 + i;
    Out_s[rb * 99 + l15] = tw0[i];
    Out_s[rb * 99 + 16 + l15] = tw1[i];
    Out_s[rb * 99 + 32 + l15] = tw2[i];
    Out_s[rb * 99 + 48 + l15] = yv[0][i];
    Out_s[rb * 99 + 64 + l15] = yv[1][i];
    Out_s[rb * 99 + 80 + l15] = yv[2][i];
  }
  __syncthreads();
  // combine -> Cbg cols t*15..t*15+14 (bf16, row stride 96)
  for (int item = tid; item < 1024; item += 256) {
    int r = item >> 4, jj = item & 15;
    int m = m0 + r;
    if (jj < 15 && m < NN) {
      const float* ob = &Out_s[r * 99];
      float gt = gate_s[r];
      float v1 = ob[jj]      + gt * (ob[48 + jj] + bY_s[jj]);
      float v2 = ob[15 + jj] + gt * (ob[64 + jj] + bY_s[15 + jj]);
      float v3 = ob[30 + jj] + gt * (ob[80 + jj] + bY_s[30 + jj]);
      Cbg[(size_t)m * 96 + t * 15 + jj] = f2bf(v1 + amp_s[r] * v2 + inv_s[r] * v3);
    }
  }
}

// ---------------- lin: Zf = Cbg @ Wlin + X0(hb@WXY) + zb; BN partial sums ----------------
__global__ __launch_bounds__(256) void k_lin(const unsigned short* __restrict__ Cbg,
                                             const unsigned short* __restrict__ hb,
                                             const unsigned short* __restrict__ WXYT_l,
                                             const unsigned short* __restrict__ WlinT_l,
                                             const float* __restrict__ zb_l,
                                             float* __restrict__ Zf,
                                             float* __restrict__ bnsum) {
  __shared__ float bnred[152];
  int tid = threadIdx.x;
  int w = tid >> 6, lane = tid & 63;
  int l15 = lane & 15, l4 = lane >> 4;
  int m0 = blockIdx.x * 64;
  if (tid < 152) bnred[tid] = 0.0f;
  __syncthreads();
  int mh = m0 + w * 16 + l15; if (mh >= NN) mh = NN - 1;
  const unsigned short* hrow = hb + (size_t)mh * 96 + l4 * 8;
  bf8_t hb0 = *(const bf8_t*)(hrow);
  bf8_t hb1 = *(const bf8_t*)(hrow + 32);
  bf8_t hb2 = *(const bf8_t*)(hrow + 64);
  const unsigned short* crow = Cbg + (size_t)mh * 96 + l4 * 8;
  bf8_t cf0 = *(const bf8_t*)(crow);
  bf8_t cf1 = *(const bf8_t*)(crow + 32);
  bf8_t cf2 = *(const bf8_t*)(crow + 64);   // cols 75..95: garbage x zero weights = 0
  #pragma unroll
  for (int fx = 0; fx < 5; ++fx) {
    int cc = fx * 16 + l15;
    const unsigned short* xp = WXYT_l + (size_t)cc * 96 + l4 * 8;
    f4_t x0 = {0.f, 0.f, 0.f, 0.f};
    x0 = __builtin_amdgcn_mfma_f32_16x16x32_bf16(hb0, *(const bf8_t*)(xp), x0, 0, 0, 0);
    x0 = __builtin_amdgcn_mfma_f32_16x16x32_bf16(hb1, *(const bf8_t*)(xp + 32), x0, 0, 0, 0);
    x0 = __builtin_amdgcn_mfma_f32_16x16x32_bf16(hb2, *(const bf8_t*)(xp + 64), x0, 0, 0, 0);
    const unsigned short* bp = WlinT_l + (size_t)cc * 96 + l4 * 8;
    f4_t acc = {0.f, 0.f, 0.f, 0.f};
    acc = __builtin_amdgcn_mfma_f32_16x16x32_bf16(cf0, *(const bf8_t*)(bp), acc, 0, 0, 0);
    acc = __builtin_amdgcn_mfma_f32_16x16x32_bf16(cf1, *(const bf8_t*)(bp + 32), acc, 0, 0, 0);
    acc = __builtin_amdgcn_mfma_f32_16x16x32_bf16(cf2, *(const bf8_t*)(bp + 64), acc, 0, 0, 0);
    if (cc < 75) {
      float s = 0.0f, q = 0.0f;
      #pragma unroll
      for (int i = 0; i < 4; ++i) {
        int m = m0 + w * 16 + l4 * 4 + i;
        if (m < NN) {
          float z = acc[i] + x0[i] + zb_l[cc];
          Zf[(size_t)m * 76 + cc] = z;
          s += z; q = fmaf(z, z, q);
        }
      }
      s += __shfl_xor(s, 16); q += __shfl_xor(q, 16);
      s += __shfl_xor(s, 32); q += __shfl_xor(q, 32);
      if (l4 == 0) {
        atomicAdd(&bnred[cc], s);
        atomicAdd(&bnred[76 + cc], q);
      }
    }
  }
  __syncthreads();
  if (tid < 75) atomicAdd(&bnsum[tid], bnred[tid]);
  else if (tid >= 76 && tid < 151) atomicAdd(&bnsum[tid - 1], bnred[tid]);
}

// ---------------- pool + MLP head (BN computed inline from bnsum) ----------------
__global__ __launch_bounds__(128) void k_pool_mlp(const float* __restrict__ Zf, const int* __restrict__ batch,
                                                  const float* __restrict__ bnsum,
                                                  const float* __restrict__ gm, const float* __restrict__ bt,
                                                  const float* __restrict__ W1, const float* __restrict__ b1,
                                                  const float* __restrict__ W2, const float* __restrict__ b2,
                                                  const float* __restrict__ W3, const float* __restrict__ b3,
                                                  float* __restrict__ out) {
  __shared__ float pooled[75];
  __shared__ float ms_s[150];
  __shared__ float z1[50];
  __shared__ float z2[25];
  __shared__ int se[2];
  int g = blockIdx.x, tid = threadIdx.x;
  if (tid < 2) {
    int target = g + tid;
    int lo = 0, hi = NN;
    while (lo < hi) { int mid = (lo + hi) >> 1; if (batch[mid] < target) lo = mid + 1; else hi = mid; }
    se[tid] = lo;
  }
  if (tid < 75) {
    float mu = bnsum[tid] * (1.0f / NN);
    float var = fmaxf(bnsum[75 + tid] * (1.0f / NN) - mu * mu, 0.0f);
    ms_s[tid] = mu;
    ms_s[75 + tid] = 1.0f / sqrtf(var + 1e-5f);
  }
  __syncthreads();
  int s = se[0], e = se[1];
  if (tid < 75) {
    float mu = ms_s[tid], sig = ms_s[75 + tid], gmc = gm[tid], btc = bt[tid];
    float acc = 0.0f;
    for (int r = s; r < e; ++r)
      acc += fmaxf(gmc * (Zf[(size_t)r * 76 + tid] - mu) * sig + btc, 0.0f);
    pooled[tid] = acc;
  }
  __syncthreads();
  if (tid < 50) {
    float acc = b1[tid];
    for (int c = 0; c < 75; ++c) acc += pooled[c] * W1[c * 50 + tid];
    z1[tid] = fmaxf(acc, 0.0f);
  }
  __syncthreads();
  if (tid < 25) {
    float acc = b2[tid];
    for (int c = 0; c < 50; ++c) acc += z1[c] * W2[c * 25 + tid];
    z2[tid] = fmaxf(acc, 0.0f);
  }
  __syncthreads();
  if (tid == 0) {
    float acc = b3[0];
    for (int c = 0; c < 25; ++c) acc += z2[c] * W3[c];
    out[g] = acc;
  }
}

// ---------------- launch ----------------
extern "C" void kernel_launch(void* const* d_in, const int* in_sizes, int n_in,
                              void* d_out, int out_size, void* d_ws, size_t ws_size,
                              hipStream_t stream) {
  const int* x = (const int*)d_in[0];
  const int* ei = (const int*)d_in[1];
  const int* eattr = (const int*)d_in[2];
  const int* batch = (const int*)d_in[3];
  const float* node_emb = (const float*)d_in[4];
  const float* edge_emb = (const float*)d_in[5];
  const float* We = (const float*)d_in[6];
  const float* be = (const float*)d_in[7];
  const float* Wpre = (const float*)d_in[8];
  const float* bpre = (const float*)d_in[9];
  const float* Wpost = (const float*)d_in[10];
  const float* bpost = (const float*)d_in[11];
  const float* Wlin = (const float*)d_in[12];
  const float* blin = (const float*)d_in[13];
  const float* gamma = (const float*)d_in[14];
  const float* beta = (const float*)d_in[15];
  const float* W1 = (const float*)d_in[16];
  const float* b1 = (const float*)d_in[17];
  const float* W2 = (const float*)d_in[18];
  const float* b2 = (const float*)d_in[19];
  const float* W3 = (const float*)d_in[20];
  const float* b3 = (const float*)d_in[21];
  float* out = (float*)d_out;

  const int* src = ei;
  const int* dst = ei + NE;

  char* p = (char*)d_ws;
  auto alloc = [&](size_t bytes) { char* r = p; p += (bytes + 255) & ~(size_t)255; return r; };
  int* deg     = (int*)alloc((size_t)NN * 4);
  int* off     = (int*)alloc((size_t)(NN + 1) * 4);
  int* cursor  = (int*)alloc((size_t)NN * 4);
  unsigned int* cpack = (unsigned int*)alloc((size_t)NE * 4);
  float* amp    = (float*)alloc((size_t)NN * 4);
  float* invamp = (float*)alloc((size_t)NN * 4);
  float* gate   = (float*)alloc((size_t)NN * 4);
  float* Zf            = (float*)alloc((size_t)NN * 76 * 4 + 256);
  unsigned short* Hsrc = (unsigned short*)alloc((size_t)NN * 400 * 2 + 256);
  unsigned short* hbv  = (unsigned short*)alloc((size_t)NN * 96 * 2 + 256);
  unsigned short* Cbg  = (unsigned short*)alloc((size_t)NN * 96 * 2 + 256);
  unsigned short* Abuf = (unsigned short*)alloc((size_t)5 * NN * 320 * 2 + 256);
  unsigned short* B1Ts   = (unsigned short*)alloc((size_t)4 * 400 * 96 * 2);
  unsigned short* WXYT   = (unsigned short*)alloc((size_t)4 * 320 * 96 * 2);
  unsigned short* WlinT  = (unsigned short*)alloc((size_t)4 * 80 * 96 * 2);
  unsigned short* WcombT = (unsigned short*)alloc((size_t)4 * 5 * 48 * 320 * 2);
  float* WXlin = (float*)alloc((size_t)4 * 5625 * 4);
  float* WY    = (float*)alloc((size_t)4 * 3 * 75 * 75 * 4);
  float* bY    = (float*)alloc((size_t)4 * 3 * 75 * 4);
  float* zb    = (float*)alloc((size_t)4 * 75 * 4);
  float* etab  = (float*)alloc((size_t)4 * 4 * 400 * 4);
  float* bnsum  = (float*)alloc((size_t)4 * 152 * 4);   // quad-buffered: region l = bnsum + l*152

  hipMemsetAsync(deg, 0, (size_t)NN * 4, stream);
  hipMemsetAsync(bnsum, 0, (size_t)4 * 152 * 4, stream);
  k_deg<<<(NE + 255) / 256, 256, 0, stream>>>(dst, deg);
  k_scan<<<1, 1024, 0, stream>>>(deg, off);
  k_amp<<<(NN + 255) / 256, 256, 0, stream>>>(deg, off, amp, invamp, gate, cursor);
  k_fill<<<(NE + 255) / 256, 256, 0, stream>>>(src, dst, eattr, cursor, cpack);
  k_embed<<<(NN * 76 + 255) / 256, 256, 0, stream>>>(x, node_emb, Zf);
  k_wxlin<<<4, 256, 0, stream>>>(Wpost, Wlin, WXlin);
  k_wy<<<60, 256, 0, stream>>>(Wpre, bpre, Wpost, WY, bY);
  k_zb<<<4, 128, 0, stream>>>(bpost, blin, Wlin, zb);
  {
    int tot = 4 * 400 * 96 + 4 * 320 * 96 + 4 * 80 * 96;
    k_packAll<<<(tot + 255) / 256, 256, 0, stream>>>(Wpre, WXlin, WY, Wlin, B1Ts, WXYT, WlinT);
  }
  k_packWcomb<<<(4 * 5 * 48 * 320 + 255) / 256, 256, 0, stream>>>(Wpost, WcombT);
  k_etab<<<16, 256, 0, stream>>>(edge_emb, We, be, Wpre, etab);

  for (int l = 0; l < NL; ++l) {
    const float* gm = gamma + (l > 0 ? (l - 1) * 75 : 0);
    const float* bt = beta + (l > 0 ? (l - 1) * 75 : 0);
    int bn = (l > 0) ? 1 : 0;
    const float* bnsum_prev = bnsum + (size_t)(l > 0 ? l - 1 : 0) * 152;
    float* bnsum_cur = bnsum + (size_t)l * 152;
    k_gemm1<<<(NN + 63) / 64, 256, 0, stream>>>(Zf, bnsum_prev, gm, bt, bn,
                                                B1Ts + (size_t)l * 400 * 96, Hsrc, hbv);
    k_gather<<<NN / 4, 256, 0, stream>>>(Hsrc, off, cpack, etab + (size_t)l * 4 * 400, Abuf);
    {
      dim3 gp(5, (NN + 63) / 64);
      k_ptower<<<gp, 256, 0, stream>>>(Abuf, hbv,
                                       WcombT + (size_t)l * 5 * 48 * 320,
                                       WXYT + (size_t)l * 320 * 96,
                                       amp, invamp, gate,
                                       bY + (size_t)l * 225, Cbg);
    }
    k_lin<<<(NN + 63) / 64, 256, 0, stream>>>(Cbg, hbv,
                                              WXYT + (size_t)l * 320 * 96,
                                              WlinT + (size_t)l * 80 * 96,
                                              zb + l * 75, Zf, bnsum_cur);
  }
  k_pool_mlp<<<NG, 128, 0, stream>>>(Zf, batch, bnsum + (size_t)(NL - 1) * 152,
                                     gamma + 225, beta + 225,
                                     W1, b1, W2, b2, W3, b3, out);
}

// Round 14
// 1072.100 us; speedup vs baseline: 1.1232x; 1.1232x over previous
//
#include <hip/hip_runtime.h>
#include <math.h>

// ---------------- problem constants ----------------
#define NN 50000      // nodes
#define NE 150000     // edges
#define NG 2000       // graphs
#define NL 4          // layers
#define AVG_DEG_LOG 1.1308269950720915f
// Hsrc/etab channel axis padded per tower: 5 towers x 80 = 400 (pad channels are exact zeros)

typedef __attribute__((ext_vector_type(8))) short bf8_t;
typedef __attribute__((ext_vector_type(4))) float f4_t;

__device__ inline unsigned short f2bf(float x) {
  union { float f; unsigned int u; } v; v.f = x;
  unsigned int r = (v.u + 0x7FFFu + ((v.u >> 16) & 1u)) >> 16;
  return (unsigned short)r;
}
__device__ inline float bflo(unsigned int u) { union { unsigned int u; float f; } v; v.u = u << 16; return v.f; }
__device__ inline float bfhi(unsigned int u) { union { unsigned int u; float f; } v; v.u = u & 0xFFFF0000u; return v.f; }

// BN(+relu)-applied bf16 fragment load from Zf row (stride 76 f32). k0 in {0,8,...,88}.
__device__ inline bf8_t ldfrag(const float* __restrict__ zrow, int k0, int bn,
                               const float* __restrict__ musig,
                               const float* __restrict__ gm, const float* __restrict__ bt) {
  bf8_t r;
  #pragma unroll
  for (int j = 0; j < 8; ++j) {
    int k = k0 + j;
    float x = 0.0f;
    if (k < 75) {
      x = zrow[k];
      if (bn) x = fmaxf(gm[k] * (x - musig[k]) * musig[75 + k] + bt[k], 0.0f);
    }
    r[j] = (short)f2bf(x);
  }
  return r;
}

// ---------------- preprocessing ----------------
__global__ void k_deg(const int* __restrict__ dst, int* __restrict__ deg) {
  int e = blockIdx.x * 256 + threadIdx.x;
  if (e < NE) atomicAdd(&deg[dst[e]], 1);
}

// multi-block scan: phase 1 — per-block (1024) exclusive scan + block sums
__global__ __launch_bounds__(1024) void k_scan1(const int* __restrict__ deg, int* __restrict__ off,
                                                int* __restrict__ bsum) {
  __shared__ int wsum[16];
  __shared__ int wpre[16];
  int tid = threadIdx.x, lane = tid & 63, wv = tid >> 6;
  int i = blockIdx.x * 1024 + tid;
  int v = (i < NN) ? deg[i] : 0;
  int incl = v;
  #pragma unroll
  for (int d = 1; d < 64; d <<= 1) { int t = __shfl_up(incl, d); if (lane >= d) incl += t; }
  if (lane == 63) wsum[wv] = incl;
  __syncthreads();
  if (wv == 0) {
    int s = (lane < 16) ? wsum[lane] : 0;
    int sc = s;
    #pragma unroll
    for (int d = 1; d < 16; d <<= 1) { int t = __shfl_up(sc, d); if (lane >= d) sc += t; }
    if (lane < 16) wpre[lane] = sc - s;
  }
  __syncthreads();
  int excl = wpre[wv] + incl - v;
  if (i < NN) off[i] = excl;
  if (tid == 1023) bsum[blockIdx.x] = excl + v;
}

// phase 2 — single wave scans the 49 block sums; writes exclusive bpre and off[NN]=total
__global__ void k_scan2(const int* __restrict__ bsum, int* __restrict__ bpre, int* __restrict__ off) {
  int lane = threadIdx.x;   // 64 threads
  int v = (lane < 49) ? bsum[lane] : 0;
  int incl = v;
  #pragma unroll
  for (int d = 1; d < 64; d <<= 1) { int t = __shfl_up(incl, d); if (lane >= d) incl += t; }
  if (lane < 49) bpre[lane] = incl - v;
  if (lane == 63) off[NN] = incl;
}

// phase 3 — add block offsets
__global__ void k_scan3(const int* __restrict__ bpre, int* __restrict__ off) {
  int i = blockIdx.x * 256 + threadIdx.x;
  if (i < NN) off[i] += bpre[i >> 10];
}

__global__ void k_amp(const int* __restrict__ deg, const int* __restrict__ off,
                      float* __restrict__ amp, float* __restrict__ invamp,
                      float* __restrict__ gate, int* __restrict__ cursor) {
  int n = blockIdx.x * 256 + threadIdx.x;
  if (n < NN) {
    int d0 = deg[n];
    int d = d0 < 1 ? 1 : d0;
    float a = logf((float)d + 1.0f) / AVG_DEG_LOG;
    amp[n] = a; invamp[n] = 1.0f / a;
    gate[n] = (d0 > 0) ? 1.0f : 0.0f;
    cursor[n] = off[n];
  }
}

__global__ void k_fill(const int* __restrict__ src, const int* __restrict__ dst,
                       const int* __restrict__ attr, int* __restrict__ cursor,
                       unsigned int* __restrict__ cpack) {
  int e = blockIdx.x * 256 + threadIdx.x;
  if (e < NE) {
    int d = dst[e];
    int p = atomicAdd(&cursor[d], 1);
    cpack[p] = (unsigned int)src[e] | ((unsigned int)attr[e] << 16);
  }
}

// node embedding -> Zf f32 [NN][76] (col 75 zero). Layer 0 reads Zf raw (bn=0).
__global__ void k_embed(const int* __restrict__ x, const float* __restrict__ emb, float* __restrict__ Zf) {
  int i = blockIdx.x * 256 + threadIdx.x;
  if (i < NN * 76) {
    int n = i / 76, c = i - (i / 76) * 76;
    Zf[i] = (c < 75) ? emb[x[n] * 75 + c] : 0.0f;
  }
}

// ---------------- weight prep ----------------
// widened: grid (4, 23)
__global__ void k_wxlin(const float* __restrict__ Wpost, const float* __restrict__ Wlin, float* __restrict__ WXlin) {
  int l = blockIdx.x;
  int idx = blockIdx.y * 256 + threadIdx.x;
  if (idx < 5625) {
    int k = idx / 75, j = idx - (idx / 75) * 75;
    float s = 0.0f;
    for (int o = 0; o < 75; ++o) {
      int t = o / 15, jj = o - t * 15;
      s += Wpost[((l * 5 + t) * 975 + k) * 15 + jj] * Wlin[l * 5625 + o * 75 + j];
    }
    WXlin[l * 5625 + idx] = s;
  }
}

__global__ void k_zb(const float* __restrict__ bpost, const float* __restrict__ blin,
                     const float* __restrict__ Wlin, float* __restrict__ zb) {
  int l = blockIdx.x, j = threadIdx.x;
  if (j < 75) {
    float s = blin[l * 75 + j];
    for (int o = 0; o < 75; ++o) s += bpost[l * 75 + o] * Wlin[l * 5625 + o * 75 + j];
    zb[l * 75 + j] = s;
  }
}

// WY[l][s][k][o], bY[l][s][o]: cd-path composed weights. grid (60, 5): slice the 1140 outputs.
__global__ void k_wy(const float* __restrict__ Wpre, const float* __restrict__ bpre,
                     const float* __restrict__ Wpost, float* __restrict__ WY, float* __restrict__ bY) {
  __shared__ float wsum[1125];
  int b = blockIdx.x;                 // l*15 + t*3 + s
  int l = b / 15, rr = b - l * 15, t = rr / 3, s = rr - (rr / 3) * 3;
  int tid = threadIdx.x;
  for (int it = tid; it < 1125; it += 256) {
    int f = it / 15, jj = it - (it / 15) * 15;
    float acc = 0.0f;
    #pragma unroll
    for (int agg = 0; agg < 3; ++agg)
      acc += Wpost[((l * 5 + t) * 975 + 75 + s * 300 + agg * 75 + f) * 15 + jj];
    wsum[f * 15 + jj] = acc;
  }
  __syncthreads();
  int it0 = blockIdx.y * 228;
  int it1 = it0 + 228;
  for (int it = it0 + tid; it < it1; it += 256) {
    int k = it / 15, jj = it - (it / 15) * 15;
    float acc = 0.0f;
    if (k < 75) {
      for (int f = 0; f < 75; ++f)
        acc += Wpre[((l * 5 + t) * 225 + k) * 75 + f] * wsum[f * 15 + jj];
      WY[((l * 3 + s) * 75 + k) * 75 + t * 15 + jj] = acc;
    } else {
      for (int f = 0; f < 75; ++f)
        acc += bpre[l * 375 + t * 75 + f] * wsum[f * 15 + jj];
      bY[(l * 3 + s) * 75 + t * 15 + jj] = acc;
    }
  }
}

// packs: B1Ts [4][400][96] (c = t*80+f, f<75 real); WXYT [4][320][96]; WlinT [4][80][96]
__global__ void k_packAll(const float* __restrict__ Wpre, const float* __restrict__ WXlin,
                          const float* __restrict__ WY, const float* __restrict__ Wlin,
                          unsigned short* __restrict__ B1Ts, unsigned short* __restrict__ WXYT,
                          unsigned short* __restrict__ WlinT) {
  const int S1 = 4 * 400 * 96;
  const int S2 = S1 + 4 * 320 * 96;
  const int S3 = S2 + 4 * 80 * 96;
  int idx = blockIdx.x * 256 + threadIdx.x;
  if (idx < S1) {
    int l = idx / (400 * 96); int rem = idx - l * (400 * 96);
    int c = rem / 96, k = rem - (rem / 96) * 96;
    int t = c / 80, f = c - t * 80;
    float v = 0.0f;
    if (f < 75 && k < 75)
      v = Wpre[((l * 5 + t) * 225 + 75 + k) * 75 + f];
    B1Ts[idx] = f2bf(v);
  } else if (idx < S2) {
    int m = idx - S1;
    int l = m / (320 * 96); int rem = m - l * (320 * 96);
    int c = rem / 96, k = rem - (rem / 96) * 96;
    float v = 0.0f;
    if (k < 75) {
      if (c < 80) {
        if (c < 75) v = WXlin[l * 5625 + k * 75 + c];
      } else {
        int g = c - 80; int t = g / 48; int r = g - t * 48; int s = r / 16; int jj = r - s * 16;
        if (jj < 15) v = WY[((l * 3 + s) * 75 + k) * 75 + t * 15 + jj];
      }
    }
    WXYT[m] = f2bf(v);
  } else if (idx < S3) {
    int m = idx - S2;
    int l = m / (80 * 96); int rem = m - l * (80 * 96);
    int j = rem / 96, k = rem - (rem / 96) * 96;
    float v = (j < 75 && k < 75) ? Wlin[l * 5625 + k * 75 + j] : 0.0f;
    WlinT[m] = f2bf(v);
  }
}

// WcombT bf16 [4][5][48][320]: row j=s*15+jj (45 real), col k = f*4+agg, f in [0,80) (f<75 real)
__global__ void k_packWcomb(const float* __restrict__ Wpost, unsigned short* __restrict__ WcombT) {
  int idx = blockIdx.x * 256 + threadIdx.x;
  if (idx >= 4 * 5 * 48 * 320) return;
  int l = idx / (5 * 48 * 320); int rem = idx - l * (5 * 48 * 320);
  int t = rem / (48 * 320); rem -= t * (48 * 320);
  int j = rem / 320, k = rem - (rem / 320) * 320;
  int f = k >> 2, agg = k & 3;
  float v = 0.0f;
  if (j < 45 && f < 75) {
    int s = j / 15, jj = j - s * 15;
    v = Wpost[((l * 5 + t) * 975 + 75 + s * 300 + agg * 75 + f) * 15 + jj];
  }
  WcombT[idx] = f2bf(v);
}

// etab f32 [4][4][400] (c = t*80+f; f>=75 pads zero)
__global__ void k_etab(const float* __restrict__ edge_emb, const float* __restrict__ We,
                       const float* __restrict__ be, const float* __restrict__ Wpre,
                       float* __restrict__ etab) {
  __shared__ float ev[75];
  int l = blockIdx.x >> 2, a = blockIdx.x & 3;
  int tid = threadIdx.x;
  if (tid < 75) {
    float acc = be[l * 75 + tid];
    for (int k = 0; k < 50; ++k) acc += edge_emb[a * 50 + k] * We[(l * 50 + k) * 75 + tid];
    ev[tid] = acc;
  }
  __syncthreads();
  for (int c = tid; c < 400; c += 256) {
    int t = c / 80, f = c - t * 80;
    float acc = 0.0f;
    if (f < 75) {
      for (int d = 0; d < 75; ++d) acc += ev[d] * Wpre[((l * 5 + t) * 225 + 150 + d) * 75 + f];
    }
    etab[(l * 4 + a) * 400 + c] = acc;
  }
}

// ---------------- GEMM1 (MFMA): Hsrc = BN(Zf) @ B1Ts -> bf16 [NN][400]; hb bf16 [NN][96]. LDS-transpose epilogue.
__global__ __launch_bounds__(256) void k_gemm1(const float* __restrict__ Zf,
                                               const float* __restrict__ bnsum,
                                               const float* __restrict__ gm, const float* __restrict__ bt,
                                               int bn,
                                               const unsigned short* __restrict__ B1Ts_l,
                                               unsigned short* __restrict__ Hsrc,
                                               unsigned short* __restrict__ hb) {
  __shared__ float ms_s[150];
  __shared__ __align__(16) unsigned short H_s[64 * 408];
  int tid = threadIdx.x;
  if (tid < 75) {
    float mu = bnsum[tid] * (1.0f / NN);
    float var = fmaxf(bnsum[75 + tid] * (1.0f / NN) - mu * mu, 0.0f);
    ms_s[tid] = mu;
    ms_s[75 + tid] = 1.0f / sqrtf(var + 1e-5f);
  }
  __syncthreads();
  int w = tid >> 6, lane = tid & 63;
  int l15 = lane & 15, l4 = lane >> 4;
  int m0 = blockIdx.x * 64;
  int mA = m0 + w * 16 + l15; if (mA >= NN) mA = NN - 1;
  const float* zrow = Zf + (size_t)mA * 76;
  bf8_t a0 = ldfrag(zrow, l4 * 8, bn, ms_s, gm, bt);
  bf8_t a1 = ldfrag(zrow, 32 + l4 * 8, bn, ms_s, gm, bt);
  bf8_t a2 = ldfrag(zrow, 64 + l4 * 8, bn, ms_s, gm, bt);
  {
    unsigned short* hrow = hb + (size_t)mA * 96 + l4 * 8;
    *(bf8_t*)(hrow) = a0;
    *(bf8_t*)(hrow + 32) = a1;
    *(bf8_t*)(hrow + 64) = a2;
  }
  for (int nf = 0; nf < 25; ++nf) {
    int c = nf * 16 + l15;
    const unsigned short* bp = B1Ts_l + (size_t)c * 96 + l4 * 8;
    f4_t acc = {0.f, 0.f, 0.f, 0.f};
    acc = __builtin_amdgcn_mfma_f32_16x16x32_bf16(a0, *(const bf8_t*)(bp), acc, 0, 0, 0);
    acc = __builtin_amdgcn_mfma_f32_16x16x32_bf16(a1, *(const bf8_t*)(bp + 32), acc, 0, 0, 0);
    acc = __builtin_amdgcn_mfma_f32_16x16x32_bf16(a2, *(const bf8_t*)(bp + 64), acc, 0, 0, 0);
    #pragma unroll
    for (int i = 0; i < 4; ++i)
      H_s[(w * 16 + l4 * 4 + i) * 408 + c] = f2bf(acc[i]);
  }
  __syncthreads();
  // flush 64 x 400 shorts via 16B stores
  for (int idx = tid; idx < 3200; idx += 256) {
    int row = idx / 50, q = idx - row * 50;
    int m = m0 + row;
    if (m < NN)
      *(uint4*)&Hsrc[(size_t)m * 400 + q * 8] = *(const uint4*)&H_s[row * 408 + q * 8];
  }
}

// ---------------- gather: 1 node/wave, 50 lanes x 8 channels (one tower each), A [5][NN][320] bf16 ----
__global__ __launch_bounds__(256) void k_gather(const unsigned short* __restrict__ Hsrc,
                                                const int* __restrict__ off,
                                                const unsigned int* __restrict__ cpack,
                                                const float* __restrict__ etab_l,
                                                unsigned short* __restrict__ A) {
  __shared__ float et_s[1600];
  int tid = threadIdx.x, w = tid >> 6, lane = tid & 63;
  for (int it = tid; it < 1600; it += 256) {
    int aa = it / 400, c = it - aa * 400;
    et_s[aa * 400 + (c ^ (((c >> 3) & 7) << 2))] = etab_l[it];
  }
  __syncthreads();
  if (lane >= 50) return;
  int g = blockIdx.x * 4 + w;
  int e0 = off[g], e1 = off[g + 1];
  int c0 = lane * 8;
  int cs = c0 ^ (((c0 >> 3) & 7) << 2);
  int t = lane / 10;
  int f0 = c0 - t * 80;
  const bf8_t* hbase = (const bf8_t*)Hsrc + lane;   // row stride 50 bf8 units
  float s8[8], q8[8], mn8[8], mx8[8];
  #pragma unroll
  for (int j = 0; j < 8; ++j) {
    s8[j] = 0.0f; q8[j] = 0.0f;
    mn8[j] = 3.402823466e+38f; mx8[j] = -3.402823466e+38f;
  }
  auto acc8 = [&](bf8_t hv, unsigned int aa) {
    union { bf8_t v; unsigned int u[4]; } cv; cv.v = hv;
    f4_t ea = *(const f4_t*)&et_s[aa * 400 + cs];
    f4_t eb = *(const f4_t*)&et_s[aa * 400 + (cs ^ 4)];
    #pragma unroll
    for (int j = 0; j < 8; ++j) {
      float h = (j & 1) ? bfhi(cv.u[j >> 1]) : bflo(cv.u[j >> 1]);
      float e = (j < 4) ? ea[j] : eb[j - 4];
      float q = h + e;
      s8[j] += q;
      q8[j] = fmaf(q, q, q8[j]);
      mn8[j] = fminf(mn8[j], q);
      mx8[j] = fmaxf(mx8[j], q);
    }
  };
  for (int e = e0; e < e1; ) {
    int m = e1 - e;
    unsigned int pk0 = cpack[e];
    unsigned int pk1 = cpack[m > 1 ? e + 1 : e];
    unsigned int pk2 = cpack[m > 2 ? e + 2 : e];
    unsigned int pk3 = cpack[m > 3 ? e + 3 : e];
    bf8_t h0 = hbase[(pk0 & 0xFFFFu) * 50];
    bf8_t h1 = hbase[(pk1 & 0xFFFFu) * 50];
    bf8_t h2 = hbase[(pk2 & 0xFFFFu) * 50];
    bf8_t h3 = hbase[(pk3 & 0xFFFFu) * 50];
    acc8(h0, pk0 >> 16);
    if (m > 1) acc8(h1, pk1 >> 16);
    if (m > 2) acc8(h2, pk2 >> 16);
    if (m > 3) acc8(h3, pk3 >> 16);
    e += (m < 4) ? m : 4;
  }
  int d = e1 - e0;
  unsigned short* abase = A + ((size_t)t * NN + g) * 320 + f0 * 4;
  uint4 pk[4];
  unsigned int* pw = (unsigned int*)pk;
  if (d > 0) {
    float inv = 1.0f / (float)d;
    #pragma unroll
    for (int j = 0; j < 8; ++j) {
      float mu = s8[j] * inv;
      float sd = sqrtf(fmaxf(q8[j] * inv - mu * mu, 0.0f) + 1e-5f);
      pw[j * 2]     = (unsigned int)f2bf(mu) | ((unsigned int)f2bf(mn8[j]) << 16);
      pw[j * 2 + 1] = (unsigned int)f2bf(mx8[j]) | ((unsigned int)f2bf(sd) << 16);
    }
  } else {
    unsigned int zsd = (unsigned int)f2bf(0.0031622776601683794f) << 16;
    #pragma unroll
    for (int j = 0; j < 8; ++j) { pw[j * 2] = 0u; pw[j * 2 + 1] = zsd; }
  }
  #pragma unroll
  for (int jj = 0; jj < 4; ++jj) *(uint4*)(abase + jj * 8) = pk[jj];
}

// ---------------- ptower: one (64-node, tower) tile per block; A@Wcomb + Y + combine -> Cbg ----------------
__global__ __launch_bounds__(256) void k_ptower(const unsigned short* __restrict__ A,
                                                const unsigned short* __restrict__ hb,
                                                const unsigned short* __restrict__ WcombT_l,
                                                const unsigned short* __restrict__ WXYT_l,
                                                const float* __restrict__ ampv,
                                                const float* __restrict__ invampv,
                                                const float* __restrict__ gatev,
                                                const float* __restrict__ bY_l,
                                                unsigned short* __restrict__ Cbg) {
  __shared__ __align__(16) float Out_s[64 * 99];   // cols 0-47 tower, 48-95 Y
  __shared__ float amp_s[64], inv_s[64], gate_s[64];
  __shared__ float bY_s[45];
  int tid = threadIdx.x;
  int w = tid >> 6, lane = tid & 63;
  int l15 = lane & 15, l4 = lane >> 4;
  int t = blockIdx.x;
  int m0 = blockIdx.y * 64;

  for (int r = tid; r < 64; r += 256) {
    int m = m0 + r; if (m >= NN) m = NN - 1;
    amp_s[r] = ampv[m]; inv_s[r] = invampv[m]; gate_s[r] = gatev[m];
  }
  if (tid < 45) {
    int s = tid / 15, jj = tid - s * 15;
    bY_s[tid] = bY_l[s * 75 + t * 15 + jj];
  }
  int mh = m0 + w * 16 + l15; if (mh >= NN) mh = NN - 1;
  const unsigned short* arow = A + ((size_t)t * NN + mh) * 320 + l4 * 8;
  bf8_t af[10];
  #pragma unroll
  for (int ks = 0; ks < 10; ++ks) af[ks] = *(const bf8_t*)(arow + ks * 32);
  const unsigned short* hrow = hb + (size_t)mh * 96 + l4 * 8;
  bf8_t hb0 = *(const bf8_t*)(hrow);
  bf8_t hb1 = *(const bf8_t*)(hrow + 32);
  bf8_t hb2 = *(const bf8_t*)(hrow + 64);

  f4_t tw0 = {0.f,0.f,0.f,0.f}, tw1 = {0.f,0.f,0.f,0.f}, tw2 = {0.f,0.f,0.f,0.f};
  const unsigned short* wp0 = WcombT_l + (size_t)(t * 48 + l15) * 320 + l4 * 8;
  const unsigned short* wp1 = WcombT_l + (size_t)(t * 48 + 16 + l15) * 320 + l4 * 8;
  const unsigned short* wp2 = WcombT_l + (size_t)(t * 48 + 32 + l15) * 320 + l4 * 8;
  #pragma unroll
  for (int ks = 0; ks < 10; ++ks) {
    tw0 = __builtin_amdgcn_mfma_f32_16x16x32_bf16(af[ks], *(const bf8_t*)(wp0 + ks * 32), tw0, 0, 0, 0);
    tw1 = __builtin_amdgcn_mfma_f32_16x16x32_bf16(af[ks], *(const bf8_t*)(wp1 + ks * 32), tw1, 0, 0, 0);
    tw2 = __builtin_amdgcn_mfma_f32_16x16x32_bf16(af[ks], *(const bf8_t*)(wp2 + ks * 32), tw2, 0, 0, 0);
  }
  f4_t yv[3];
  #pragma unroll
  for (int s = 0; s < 3; ++s) {
    const unsigned short* bp = WXYT_l + (size_t)(80 + t * 48 + s * 16 + l15) * 96 + l4 * 8;
    f4_t acc = {0.f, 0.f, 0.f, 0.f};
    acc = __builtin_amdgcn_mfma_f32_16x16x32_bf16(hb0, *(const bf8_t*)(bp), acc, 0, 0, 0);
    acc = __builtin_amdgcn_mfma_f32_16x16x32_bf16(hb1, *(const bf8_t*)(bp + 32), acc, 0, 0, 0);
    acc = __builtin_amdgcn_mfma_f32_16x16x32_bf16(hb2, *(const bf8_t*)(bp + 64), acc, 0, 0, 0);
    yv[s] = acc;
  }
  #pragma unroll
  for (int i = 0; i < 4; ++i) {
    int rb = w * 16 + l4 * 4 + i;
    Out_s[rb * 99 + l15] = tw0[i];
    Out_s[rb * 99 + 16 + l15] = tw1[i];
    Out_s[rb * 99 + 32 + l15] = tw2[i];
    Out_s[rb * 99 + 48 + l15] = yv[0][i];
    Out_s[rb * 99 + 64 + l15] = yv[1][i];
    Out_s[rb * 99 + 80 + l15] = yv[2][i];
  }
  __syncthreads();
  // combine -> Cbg cols t*15..t*15+14 (bf16, row stride 96)
  for (int item = tid; item < 1024; item += 256) {
    int r = item >> 4, jj = item & 15;
    int m = m0 + r;
    if (jj < 15 && m < NN) {
      const float* ob = &Out_s[r * 99];
      float gt = gate_s[r];
      float v1 = ob[jj]      + gt * (ob[48 + jj] + bY_s[jj]);
      float v2 = ob[15 + jj] + gt * (ob[64 + jj] + bY_s[15 + jj]);
      float v3 = ob[30 + jj] + gt * (ob[80 + jj] + bY_s[30 + jj]);
      Cbg[(size_t)m * 96 + t * 15 + jj] = f2bf(v1 + amp_s[r] * v2 + inv_s[r] * v3);
    }
  }
}

// ---------------- lin: Zf = Cbg @ Wlin + X0(hb@WXY) + zb; BN partial sums ----------------
__global__ __launch_bounds__(256) void k_lin(const unsigned short* __restrict__ Cbg,
                                             const unsigned short* __restrict__ hb,
                                             const unsigned short* __restrict__ WXYT_l,
                                             const unsigned short* __restrict__ WlinT_l,
                                             const float* __restrict__ zb_l,
                                             float* __restrict__ Zf,
                                             float* __restrict__ bnsum) {
  __shared__ float bnred[152];
  int tid = threadIdx.x;
  int w = tid >> 6, lane = tid & 63;
  int l15 = lane & 15, l4 = lane >> 4;
  int m0 = blockIdx.x * 64;
  if (tid < 152) bnred[tid] = 0.0f;
  __syncthreads();
  int mh = m0 + w * 16 + l15; if (mh >= NN) mh = NN - 1;
  const unsigned short* hrow = hb + (size_t)mh * 96 + l4 * 8;
  bf8_t hb0 = *(const bf8_t*)(hrow);
  bf8_t hb1 = *(const bf8_t*)(hrow + 32);
  bf8_t hb2 = *(const bf8_t*)(hrow + 64);
  const unsigned short* crow = Cbg + (size_t)mh * 96 + l4 * 8;
  bf8_t cf0 = *(const bf8_t*)(crow);
  bf8_t cf1 = *(const bf8_t*)(crow + 32);
  bf8_t cf2 = *(const bf8_t*)(crow + 64);   // cols 75..95: garbage x zero weights = 0
  #pragma unroll
  for (int fx = 0; fx < 5; ++fx) {
    int cc = fx * 16 + l15;
    const unsigned short* xp = WXYT_l + (size_t)cc * 96 + l4 * 8;
    f4_t x0 = {0.f, 0.f, 0.f, 0.f};
    x0 = __builtin_amdgcn_mfma_f32_16x16x32_bf16(hb0, *(const bf8_t*)(xp), x0, 0, 0, 0);
    x0 = __builtin_amdgcn_mfma_f32_16x16x32_bf16(hb1, *(const bf8_t*)(xp + 32), x0, 0, 0, 0);
    x0 = __builtin_amdgcn_mfma_f32_16x16x32_bf16(hb2, *(const bf8_t*)(xp + 64), x0, 0, 0, 0);
    const unsigned short* bp = WlinT_l + (size_t)cc * 96 + l4 * 8;
    f4_t acc = {0.f, 0.f, 0.f, 0.f};
    acc = __builtin_amdgcn_mfma_f32_16x16x32_bf16(cf0, *(const bf8_t*)(bp), acc, 0, 0, 0);
    acc = __builtin_amdgcn_mfma_f32_16x16x32_bf16(cf1, *(const bf8_t*)(bp + 32), acc, 0, 0, 0);
    acc = __builtin_amdgcn_mfma_f32_16x16x32_bf16(cf2, *(const bf8_t*)(bp + 64), acc, 0, 0, 0);
    if (cc < 75) {
      float s = 0.0f, q = 0.0f;
      #pragma unroll
      for (int i = 0; i < 4; ++i) {
        int m = m0 + w * 16 + l4 * 4 + i;
        if (m < NN) {
          float z = acc[i] + x0[i] + zb_l[cc];
          Zf[(size_t)m * 76 + cc] = z;
          s += z; q = fmaf(z, z, q);
        }
      }
      s += __shfl_xor(s, 16); q += __shfl_xor(q, 16);
      s += __shfl_xor(s, 32); q += __shfl_xor(q, 32);
      if (l4 == 0) {
        atomicAdd(&bnred[cc], s);
        atomicAdd(&bnred[76 + cc], q);
      }
    }
  }
  __syncthreads();
  if (tid < 75) atomicAdd(&bnsum[tid], bnred[tid]);
  else if (tid >= 76 && tid < 151) atomicAdd(&bnsum[tid - 1], bnred[tid]);
}

// ---------------- pool + MLP head (BN computed inline from bnsum) ----------------
__global__ __launch_bounds__(128) void k_pool_mlp(const float* __restrict__ Zf, const int* __restrict__ batch,
                                                  const float* __restrict__ bnsum,
                                                  const float* __restrict__ gm, const float* __restrict__ bt,
                                                  const float* __restrict__ W1, const float* __restrict__ b1,
                                                  const float* __restrict__ W2, const float* __restrict__ b2,
                                                  const float* __restrict__ W3, const float* __restrict__ b3,
                                                  float* __restrict__ out) {
  __shared__ float pooled[75];
  __shared__ float ms_s[150];
  __shared__ float z1[50];
  __shared__ float z2[25];
  __shared__ int se[2];
  int g = blockIdx.x, tid = threadIdx.x;
  if (tid < 2) {
    int target = g + tid;
    int lo = 0, hi = NN;
    while (lo < hi) { int mid = (lo + hi) >> 1; if (batch[mid] < target) lo = mid + 1; else hi = mid; }
    se[tid] = lo;
  }
  if (tid < 75) {
    float mu = bnsum[tid] * (1.0f / NN);
    float var = fmaxf(bnsum[75 + tid] * (1.0f / NN) - mu * mu, 0.0f);
    ms_s[tid] = mu;
    ms_s[75 + tid] = 1.0f / sqrtf(var + 1e-5f);
  }
  __syncthreads();
  int s = se[0], e = se[1];
  if (tid < 75) {
    float mu = ms_s[tid], sig = ms_s[75 + tid], gmc = gm[tid], btc = bt[tid];
    float acc = 0.0f;
    for (int r = s; r < e; ++r)
      acc += fmaxf(gmc * (Zf[(size_t)r * 76 + tid] - mu) * sig + btc, 0.0f);
    pooled[tid] = acc;
  }
  __syncthreads();
  if (tid < 50) {
    float acc = b1[tid];
    for (int c = 0; c < 75; ++c) acc += pooled[c] * W1[c * 50 + tid];
    z1[tid] = fmaxf(acc, 0.0f);
  }
  __syncthreads();
  if (tid < 25) {
    float acc = b2[tid];
    for (int c = 0; c < 50; ++c) acc += z1[c] * W2[c * 25 + tid];
    z2[tid] = fmaxf(acc, 0.0f);
  }
  __syncthreads();
  if (tid == 0) {
    float acc = b3[0];
    for (int c = 0; c < 25; ++c) acc += z2[c] * W3[c];
    out[g] = acc;
  }
}

// ---------------- launch ----------------
extern "C" void kernel_launch(void* const* d_in, const int* in_sizes, int n_in,
                              void* d_out, int out_size, void* d_ws, size_t ws_size,
                              hipStream_t stream) {
  const int* x = (const int*)d_in[0];
  const int* ei = (const int*)d_in[1];
  const int* eattr = (const int*)d_in[2];
  const int* batch = (const int*)d_in[3];
  const float* node_emb = (const float*)d_in[4];
  const float* edge_emb = (const float*)d_in[5];
  const float* We = (const float*)d_in[6];
  const float* be = (const float*)d_in[7];
  const float* Wpre = (const float*)d_in[8];
  const float* bpre = (const float*)d_in[9];
  const float* Wpost = (const float*)d_in[10];
  const float* bpost = (const float*)d_in[11];
  const float* Wlin = (const float*)d_in[12];
  const float* blin = (const float*)d_in[13];
  const float* gamma = (const float*)d_in[14];
  const float* beta = (const float*)d_in[15];
  const float* W1 = (const float*)d_in[16];
  const float* b1 = (const float*)d_in[17];
  const float* W2 = (const float*)d_in[18];
  const float* b2 = (const float*)d_in[19];
  const float* W3 = (const float*)d_in[20];
  const float* b3 = (const float*)d_in[21];
  float* out = (float*)d_out;

  const int* src = ei;
  const int* dst = ei + NE;

  char* p = (char*)d_ws;
  auto alloc = [&](size_t bytes) { char* r = p; p += (bytes + 255) & ~(size_t)255; return r; };
  int* deg     = (int*)alloc((size_t)NN * 4);
  int* off     = (int*)alloc((size_t)(NN + 1) * 4);
  int* cursor  = (int*)alloc((size_t)NN * 4);
  int* bsum    = (int*)alloc((size_t)64 * 4);
  int* bpre2   = (int*)alloc((size_t)64 * 4);
  unsigned int* cpack = (unsigned int*)alloc((size_t)NE * 4);
  float* amp    = (float*)alloc((size_t)NN * 4);
  float* invamp = (float*)alloc((size_t)NN * 4);
  float* gate   = (float*)alloc((size_t)NN * 4);
  float* Zf            = (float*)alloc((size_t)NN * 76 * 4 + 256);
  unsigned short* Hsrc = (unsigned short*)alloc((size_t)NN * 400 * 2 + 256);
  unsigned short* hbv  = (unsigned short*)alloc((size_t)NN * 96 * 2 + 256);
  unsigned short* Cbg  = (unsigned short*)alloc((size_t)NN * 96 * 2 + 256);
  unsigned short* Abuf = (unsigned short*)alloc((size_t)5 * NN * 320 * 2 + 256);
  unsigned short* B1Ts   = (unsigned short*)alloc((size_t)4 * 400 * 96 * 2);
  unsigned short* WXYT   = (unsigned short*)alloc((size_t)4 * 320 * 96 * 2);
  unsigned short* WlinT  = (unsigned short*)alloc((size_t)4 * 80 * 96 * 2);
  unsigned short* WcombT = (unsigned short*)alloc((size_t)4 * 5 * 48 * 320 * 2);
  float* WXlin = (float*)alloc((size_t)4 * 5625 * 4);
  float* WY    = (float*)alloc((size_t)4 * 3 * 75 * 75 * 4);
  float* bY    = (float*)alloc((size_t)4 * 3 * 75 * 4);
  float* zb    = (float*)alloc((size_t)4 * 75 * 4);
  float* etab  = (float*)alloc((size_t)4 * 4 * 400 * 4);
  float* bnsum  = (float*)alloc((size_t)4 * 152 * 4);   // quad-buffered: region l = bnsum + l*152

  hipMemsetAsync(deg, 0, (size_t)NN * 4, stream);
  hipMemsetAsync(bnsum, 0, (size_t)4 * 152 * 4, stream);
  k_deg<<<(NE + 255) / 256, 256, 0, stream>>>(dst, deg);
  k_scan1<<<(NN + 1023) / 1024, 1024, 0, stream>>>(deg, off, bsum);
  k_scan2<<<1, 64, 0, stream>>>(bsum, bpre2, off);
  k_scan3<<<(NN + 255) / 256, 256, 0, stream>>>(bpre2, off);
  k_amp<<<(NN + 255) / 256, 256, 0, stream>>>(deg, off, amp, invamp, gate, cursor);
  k_fill<<<(NE + 255) / 256, 256, 0, stream>>>(src, dst, eattr, cursor, cpack);
  k_embed<<<(NN * 76 + 255) / 256, 256, 0, stream>>>(x, node_emb, Zf);
  k_wxlin<<<dim3(4, 23), 256, 0, stream>>>(Wpost, Wlin, WXlin);
  k_wy<<<dim3(60, 5), 256, 0, stream>>>(Wpre, bpre, Wpost, WY, bY);
  k_zb<<<4, 128, 0, stream>>>(bpost, blin, Wlin, zb);
  {
    int tot = 4 * 400 * 96 + 4 * 320 * 96 + 4 * 80 * 96;
    k_packAll<<<(tot + 255) / 256, 256, 0, stream>>>(Wpre, WXlin, WY, Wlin, B1Ts, WXYT, WlinT);
  }
  k_packWcomb<<<(4 * 5 * 48 * 320 + 255) / 256, 256, 0, stream>>>(Wpost, WcombT);
  k_etab<<<16, 256, 0, stream>>>(edge_emb, We, be, Wpre, etab);

  for (int l = 0; l < NL; ++l) {
    const float* gm = gamma + (l > 0 ? (l - 1) * 75 : 0);
    const float* bt = beta + (l > 0 ? (l - 1) * 75 : 0);
    int bn = (l > 0) ? 1 : 0;
    const float* bnsum_prev = bnsum + (size_t)(l > 0 ? l - 1 : 0) * 152;
    float* bnsum_cur = bnsum + (size_t)l * 152;
    k_gemm1<<<(NN + 63) / 64, 256, 0, stream>>>(Zf, bnsum_prev, gm, bt, bn,
                                                B1Ts + (size_t)l * 400 * 96, Hsrc, hbv);
    k_gather<<<NN / 4, 256, 0, stream>>>(Hsrc, off, cpack, etab + (size_t)l * 4 * 400, Abuf);
    {
      dim3 gp(5, (NN + 63) / 64);
      k_ptower<<<gp, 256, 0, stream>>>(Abuf, hbv,
                                       WcombT + (size_t)l * 5 * 48 * 320,
                                       WXYT + (size_t)l * 320 * 96,
                                       amp, invamp, gate,
                                       bY + (size_t)l * 225, Cbg);
    }
    k_lin<<<(NN + 63) / 64, 256, 0, stream>>>(Cbg, hbv,
                                              WXYT + (size_t)l * 320 * 96,
                                              WlinT + (size_t)l * 80 * 96,
                                              zb + l * 75, Zf, bnsum_cur);
  }
  k_pool_mlp<<<NG, 128, 0, stream>>>(Zf, batch, bnsum + (size_t)(NL - 1) * 152,
                                     gamma + 225, beta + 225,
                                     W1, b1, W2, b2, W3, b3, out);
}